// Round 2
// baseline (1948.343 us; speedup 1.0000x reference)
//
#include <hip/hip_runtime.h>

typedef unsigned short u16;
typedef unsigned int u32;
typedef float f32x4 __attribute__((ext_vector_type(4)));
typedef short bfx8 __attribute__((ext_vector_type(8)));

#define D_DIM 512

__device__ __forceinline__ float bits2f(u32 b) {
    return __uint_as_float(b << 16);
}
__device__ __forceinline__ u16 f2b_bits(float f) {
    u32 u = __float_as_uint(f);
    u32 r = (u + 0x7fffu + ((u >> 16) & 1u)) >> 16;  // RNE
    return (u16)r;
}

// ---------------- degree count ----------------
__global__ void count_k(const int* __restrict__ dst, int* __restrict__ cnt, int E) {
    int i = blockIdx.x * 256 + threadIdx.x;
    if (i < E) atomicAdd(&cnt[dst[i]], 1);
}

// ---------------- weight transpose f32 -> bf16 ----------------
// WtC[n][k] (512 x 1024): k<512 -> W_aa[k][n], else W_ba[k-512][n]
// WtAb[n][k] (512 x 512): W_ab[k][n]
__global__ void prep_wt(const float* __restrict__ Waa, const float* __restrict__ Wba,
                        const float* __restrict__ Wab,
                        u16* __restrict__ WtC, u16* __restrict__ WtAb) {
    int idx = blockIdx.x * 256 + threadIdx.x;
    if (idx < 512 * 1024) {
        int n = idx >> 10, k = idx & 1023;
        float v = (k < 512) ? Waa[k * 512 + n] : Wba[(k - 512) * 512 + n];
        WtC[idx] = f2b_bits(v);
    } else {
        int idx2 = idx - 512 * 1024;
        int n = idx2 >> 9, k = idx2 & 511;
        WtAb[idx2] = f2b_bits(Wab[k * 512 + n]);
    }
}

// ---------------- scatter-mean (wave per edge) ----------------
// agg[dst] += bf16(feat[src] * (1/max(cnt[dst],1))), bf16 pk atomics
__global__ __launch_bounds__(256) void scatter_k(
    const float* __restrict__ feat, const int* __restrict__ src,
    const int* __restrict__ dst, const int* __restrict__ cnt,
    u16* __restrict__ agg, int ld, int colOff, int E) {
    int wid = threadIdx.x >> 6, lane = threadIdx.x & 63;
    int e = blockIdx.x * 4 + wid;
    if (e >= E) return;
    int s = src[e], d = dst[e];
    int c = cnt[d];
    float rc = 1.0f / (float)(c > 1 ? c : 1);
    const float* fp = feat + (size_t)s * D_DIM + lane * 8;
    u16* ap = agg + (size_t)d * ld + colOff + lane * 8;
    f32x4 v0 = *(const f32x4*)fp;
    f32x4 v1 = *(const f32x4*)(fp + 4);
    float vals[8] = {v0[0], v0[1], v0[2], v0[3], v1[0], v1[1], v1[2], v1[3]};
#pragma unroll
    for (int i = 0; i < 4; i++) {
        float lo = vals[2 * i] * rc;
        float hi = vals[2 * i + 1] * rc;
        u32 pk = ((u32)f2b_bits(hi) << 16) | (u32)f2b_bits(lo);
        u16* p = ap + 2 * i;
        asm volatile("global_atomic_pk_add_bf16 %0, %1, off"
                     :: "v"(p), "v"(pk) : "memory");
    }
}

// ---------------- bf16 MFMA GEMM, f32 out ----------------
// out[m][n] = sum_k A[m][k] * Bt[n][k]  (+ cnt-masked f32 biases)
// A: M x KT row-major bf16, Bt: 512 x KT row-major bf16.
// 128x128 tile, BK=64, 4 waves (each 64x64), 16x16x32 MFMA.
// LDS XOR-swizzle: 16B chunk c' = c ^ (row&7); staged via pre-swizzled
// global source addresses (global_load_lds dest must stay linear).
template <int KT>
__global__ __launch_bounds__(256) void gemm_bias(
    const u16* __restrict__ A, const u16* __restrict__ Bt,
    float* __restrict__ out,
    const float* __restrict__ bias0, const int* __restrict__ cnt0,
    const float* __restrict__ bias1, const int* __restrict__ cnt1,
    int M) {
    constexpr int BK = 64;  // elements; row = 128B = 8 x 16B chunks
    __shared__ __align__(16) u16 As[128 * BK];
    __shared__ __align__(16) u16 Bs[128 * BK];

    int tid = threadIdx.x;
    int wid = tid >> 6, lane = tid & 63;
    int tileM = blockIdx.x * 128, tileN = blockIdx.y * 128;
    int wm = wid >> 1, wn = wid & 1;
    int m0 = wm * 64, n0 = wn * 64;

    // staging geometry: instr jj covers 8 rows; lane -> (row_in=l>>3, c'=l&7)
    int l8 = lane >> 3;
    int cc = (lane & 7) ^ l8;  // logical chunk for this lane (pre-swizzled src)

    f32x4 acc[4][4] = {};

    int lq = lane >> 4, lr = lane & 15;

    for (int k0 = 0; k0 < KT; k0 += BK) {
#pragma unroll
        for (int i = 0; i < 4; i++) {
            int jj = wid * 4 + i;
            int row = tileM + jj * 8 + l8;
            if (row > M - 1) row = M - 1;
            const u16* src = A + (size_t)row * KT + k0 + cc * 8;
            __builtin_amdgcn_global_load_lds(
                (const __attribute__((address_space(1))) void*)src,
                (__attribute__((address_space(3))) void*)&As[jj * 8 * BK],
                16, 0, 0);
        }
#pragma unroll
        for (int i = 0; i < 4; i++) {
            int jj = wid * 4 + i;
            int nrow = tileN + jj * 8 + l8;
            const u16* src = Bt + (size_t)nrow * KT + k0 + cc * 8;
            __builtin_amdgcn_global_load_lds(
                (const __attribute__((address_space(1))) void*)src,
                (__attribute__((address_space(3))) void*)&Bs[jj * 8 * BK],
                16, 0, 0);
        }
        __syncthreads();

#pragma unroll
        for (int kk = 0; kk < 2; kk++) {
            bfx8 a[4], b[4];
#pragma unroll
            for (int m = 0; m < 4; m++) {
                int r = m0 + m * 16 + lr;
                int cp = ((kk << 2) | lq) ^ (r & 7);
                a[m] = *(const bfx8*)&As[r * BK + cp * 8];
            }
#pragma unroll
            for (int n = 0; n < 4; n++) {
                int r = n0 + n * 16 + lr;
                int cp = ((kk << 2) | lq) ^ (r & 7);
                b[n] = *(const bfx8*)&Bs[r * BK + cp * 8];
            }
#pragma unroll
            for (int m = 0; m < 4; m++)
#pragma unroll
                for (int n = 0; n < 4; n++)
                    acc[m][n] = __builtin_amdgcn_mfma_f32_16x16x32_bf16(
                        a[m], b[n], acc[m][n], 0, 0, 0);
        }
        __syncthreads();
    }

    // epilogue: D row = (lane>>4)*4 + reg, col = lane&15 (m89-verified)
#pragma unroll
    for (int m = 0; m < 4; m++) {
#pragma unroll
        for (int r = 0; r < 4; r++) {
            int row = tileM + m0 + m * 16 + lq * 4 + r;
            if (row >= M) continue;
            bool q0 = cnt0 && (cnt0[row] > 0);
            bool q1 = cnt1 && (cnt1[row] > 0);
#pragma unroll
            for (int n = 0; n < 4; n++) {
                int col = tileN + n0 + n * 16 + lr;
                float v = acc[m][n][r];
                if (q0) v += bias0[col];
                if (q1) v += bias1[col];
                out[(size_t)row * D_DIM + col] = v;
            }
        }
    }
}

extern "C" void kernel_launch(void* const* d_in, const int* in_sizes, int n_in,
                              void* d_out, int out_size, void* d_ws, size_t ws_size,
                              hipStream_t stream) {
    const float* featA = (const float*)d_in[0];
    const float* featB = (const float*)d_in[1];
    const float* Waa = (const float*)d_in[2];
    const float* baa = (const float*)d_in[3];
    const float* Wab = (const float*)d_in[4];
    const float* bab = (const float*)d_in[5];
    const float* Wba = (const float*)d_in[6];
    const float* bba = (const float*)d_in[7];
    const int* src_aa = (const int*)d_in[8];
    const int* dst_aa = (const int*)d_in[9];
    const int* src_ab = (const int*)d_in[10];
    const int* dst_ab = (const int*)d_in[11];
    const int* src_ba = (const int*)d_in[12];
    const int* dst_ba = (const int*)d_in[13];

    int NA = in_sizes[0] / D_DIM, NB = in_sizes[1] / D_DIM;
    int Eaa = in_sizes[8], Eab = in_sizes[10], Eba = in_sizes[12];

    float* out = (float*)d_out;
    char* ws = (char*)d_ws;
    size_t off = 0;
    u16* Acat = (u16*)(ws + off); off += (size_t)NA * 1024 * 2;   // [NA][1024]: aa | ba
    u16* Aab  = (u16*)(ws + off); off += (size_t)NB * 512 * 2;    // [NB][512]
    u16* WtC  = (u16*)(ws + off); off += (size_t)512 * 1024 * 2;  // [512][1024]
    u16* WtAb = (u16*)(ws + off); off += (size_t)512 * 512 * 2;   // [512][512]
    int* cnt_aa = (int*)(ws + off); off += (size_t)NA * 4;
    int* cnt_ba = (int*)(ws + off); off += (size_t)NA * 4;
    int* cnt_ab = (int*)(ws + off); off += (size_t)NB * 4;

    // zero aggregates (contiguous) and counts (contiguous)
    hipMemsetAsync(Acat, 0, (size_t)NA * 1024 * 2 + (size_t)NB * 512 * 2, stream);
    hipMemsetAsync(cnt_aa, 0, (size_t)(2 * NA + NB) * 4, stream);

    count_k<<<(Eaa + 255) / 256, 256, 0, stream>>>(dst_aa, cnt_aa, Eaa);
    count_k<<<(Eba + 255) / 256, 256, 0, stream>>>(dst_ba, cnt_ba, Eba);
    count_k<<<(Eab + 255) / 256, 256, 0, stream>>>(dst_ab, cnt_ab, Eab);

    prep_wt<<<(512 * 1024 + 512 * 512) / 256, 256, 0, stream>>>(Waa, Wba, Wab, WtC, WtAb);

    scatter_k<<<(Eaa + 3) / 4, 256, 0, stream>>>(featA, src_aa, dst_aa, cnt_aa,
                                                 Acat, 1024, 0, Eaa);
    scatter_k<<<(Eba + 3) / 4, 256, 0, stream>>>(featB, src_ba, dst_ba, cnt_ba,
                                                 Acat, 1024, 512, Eba);
    scatter_k<<<(Eab + 3) / 4, 256, 0, stream>>>(featA, src_ab, dst_ab, cnt_ab,
                                                 Aab, 512, 0, Eab);

    dim3 blk(256);
    dim3 g1((NA + 127) / 128, 512 / 128);
    gemm_bias<1024><<<g1, blk, 0, stream>>>(Acat, WtC, out, baa, cnt_aa, bba, cnt_ba, NA);
    dim3 g2((NB + 127) / 128, 512 / 128);
    gemm_bias<512><<<g2, blk, 0, stream>>>(Aab, WtAb, out + (size_t)NA * D_DIM,
                                           bab, cnt_ab, nullptr, nullptr, NB);
}

// Round 3
// 598.853 us; speedup vs baseline: 3.2535x; 3.2535x over previous
//
#include <hip/hip_runtime.h>

typedef unsigned short u16;
typedef unsigned int u32;
typedef float f32x4 __attribute__((ext_vector_type(4)));
typedef short bfx8 __attribute__((ext_vector_type(8)));

#define D_DIM 512

__device__ __forceinline__ float bits2f(u32 b) {
    return __uint_as_float(b << 16);
}
__device__ __forceinline__ u16 f2b_bits(float f) {
    u32 u = __float_as_uint(f);
    u32 r = (u + 0x7fffu + ((u >> 16) & 1u)) >> 16;  // RNE
    return (u16)r;
}

// ---------------- degree count ----------------
__global__ void count_k(const int* __restrict__ dst, int* __restrict__ cnt, int E) {
    int i = blockIdx.x * 256 + threadIdx.x;
    if (i < E) atomicAdd(&cnt[dst[i]], 1);
}

// ---------------- exclusive prefix-sum into cursor ----------------
// 3 blocks, one per etype; block-wide Hillis-Steele over 1024-chunks.
__global__ __launch_bounds__(1024) void scan_k(
    const int* __restrict__ c0, int* __restrict__ o0, int n0,
    const int* __restrict__ c1, int* __restrict__ o1, int n1,
    const int* __restrict__ c2, int* __restrict__ o2, int n2) {
    const int* cnt = (blockIdx.x == 0) ? c0 : (blockIdx.x == 1) ? c1 : c2;
    int* cur = (blockIdx.x == 0) ? o0 : (blockIdx.x == 1) ? o1 : o2;
    int N = (blockIdx.x == 0) ? n0 : (blockIdx.x == 1) ? n1 : n2;
    __shared__ int buf[1024];
    __shared__ int carry;
    int tid = threadIdx.x;
    if (tid == 0) carry = 0;
    __syncthreads();
    for (int base = 0; base < N; base += 1024) {
        int v = (base + tid < N) ? cnt[base + tid] : 0;
        buf[tid] = v;
        __syncthreads();
#pragma unroll
        for (int d = 1; d < 1024; d <<= 1) {
            int t = (tid >= d) ? buf[tid - d] : 0;
            __syncthreads();
            buf[tid] += t;
            __syncthreads();
        }
        int incl = buf[tid];
        if (base + tid < N) cur[base + tid] = carry + incl - v;  // exclusive
        __syncthreads();
        if (tid == 0) carry += buf[1023];
        __syncthreads();
    }
}

// ---------------- CSR bucket fill ----------------
// after this, cur[d] = inclusive prefix (end of bucket d)
__global__ void fill_k(const int* __restrict__ src, const int* __restrict__ dst,
                       int* __restrict__ cur, int* __restrict__ csr, int E) {
    int i = blockIdx.x * 256 + threadIdx.x;
    if (i < E) {
        int slot = atomicAdd(&cur[dst[i]], 1);
        csr[slot] = src[i];
    }
}

// ---------------- pull-mean (wave per dst node) ----------------
// agg[node][colOff + lane*8 .. +8] = bf16(mean of feat[src] rows)
__global__ __launch_bounds__(256) void pull_k(
    const float* __restrict__ feat, const int* __restrict__ cur,
    const int* __restrict__ cnt, const int* __restrict__ csr,
    u16* __restrict__ agg, int ld, int colOff, int N) {
    int wid = threadIdx.x >> 6, lane = threadIdx.x & 63;
    int node = blockIdx.x * 4 + wid;
    if (node >= N) return;
    int end = cur[node];
    int c = cnt[node];
    int beg = end - c;
    float acc[8] = {};
    for (int j = beg; j < end; j++) {
        int s = csr[j];
        const float* fp = feat + (size_t)s * D_DIM + lane * 8;
        f32x4 v0 = *(const f32x4*)fp;
        f32x4 v1 = *(const f32x4*)(fp + 4);
        acc[0] += v0[0]; acc[1] += v0[1]; acc[2] += v0[2]; acc[3] += v0[3];
        acc[4] += v1[0]; acc[5] += v1[1]; acc[6] += v1[2]; acc[7] += v1[3];
    }
    float rc = 1.0f / (float)(c > 1 ? c : 1);
    u16* ap = agg + (size_t)node * ld + colOff + lane * 8;
    u16 o[8];
#pragma unroll
    for (int i = 0; i < 8; i++) o[i] = f2b_bits(acc[i] * rc);
    *(bfx8*)ap = *(bfx8*)o;
}

// ---------------- weight transpose f32 -> bf16 ----------------
__global__ void prep_wt(const float* __restrict__ Waa, const float* __restrict__ Wba,
                        const float* __restrict__ Wab,
                        u16* __restrict__ WtC, u16* __restrict__ WtAb) {
    int idx = blockIdx.x * 256 + threadIdx.x;
    if (idx < 512 * 1024) {
        int n = idx >> 10, k = idx & 1023;
        float v = (k < 512) ? Waa[k * 512 + n] : Wba[(k - 512) * 512 + n];
        WtC[idx] = f2b_bits(v);
    } else {
        int idx2 = idx - 512 * 1024;
        int n = idx2 >> 9, k = idx2 & 511;
        WtAb[idx2] = f2b_bits(Wab[k * 512 + n]);
    }
}

// ---------------- bf16 MFMA GEMM, f32 out ----------------
// out[m][n] = sum_k A[m][k] * Bt[n][k]  (+ cnt-masked f32 biases)
// 128x128 tile, BK=64, 4 waves, 16x16x32 MFMA, XOR-swizzled LDS.
template <int KT>
__global__ __launch_bounds__(256) void gemm_bias(
    const u16* __restrict__ A, const u16* __restrict__ Bt,
    float* __restrict__ out,
    const float* __restrict__ bias0, const int* __restrict__ cnt0,
    const float* __restrict__ bias1, const int* __restrict__ cnt1,
    int M) {
    constexpr int BK = 64;
    __shared__ __align__(16) u16 As[128 * BK];
    __shared__ __align__(16) u16 Bs[128 * BK];

    int tid = threadIdx.x;
    int wid = tid >> 6, lane = tid & 63;
    int tileM = blockIdx.x * 128, tileN = blockIdx.y * 128;
    int wm = wid >> 1, wn = wid & 1;
    int m0 = wm * 64, n0 = wn * 64;

    int l8 = lane >> 3;
    int cc = (lane & 7) ^ l8;

    f32x4 acc[4][4] = {};
    int lq = lane >> 4, lr = lane & 15;

    for (int k0 = 0; k0 < KT; k0 += BK) {
#pragma unroll
        for (int i = 0; i < 4; i++) {
            int jj = wid * 4 + i;
            int row = tileM + jj * 8 + l8;
            if (row > M - 1) row = M - 1;
            const u16* src = A + (size_t)row * KT + k0 + cc * 8;
            __builtin_amdgcn_global_load_lds(
                (const __attribute__((address_space(1))) void*)src,
                (__attribute__((address_space(3))) void*)&As[jj * 8 * BK],
                16, 0, 0);
        }
#pragma unroll
        for (int i = 0; i < 4; i++) {
            int jj = wid * 4 + i;
            int nrow = tileN + jj * 8 + l8;
            const u16* src = Bt + (size_t)nrow * KT + k0 + cc * 8;
            __builtin_amdgcn_global_load_lds(
                (const __attribute__((address_space(1))) void*)src,
                (__attribute__((address_space(3))) void*)&Bs[jj * 8 * BK],
                16, 0, 0);
        }
        __syncthreads();

#pragma unroll
        for (int kk = 0; kk < 2; kk++) {
            bfx8 a[4], b[4];
#pragma unroll
            for (int m = 0; m < 4; m++) {
                int r = m0 + m * 16 + lr;
                int cp = ((kk << 2) | lq) ^ (r & 7);
                a[m] = *(const bfx8*)&As[r * BK + cp * 8];
            }
#pragma unroll
            for (int n = 0; n < 4; n++) {
                int r = n0 + n * 16 + lr;
                int cp = ((kk << 2) | lq) ^ (r & 7);
                b[n] = *(const bfx8*)&Bs[r * BK + cp * 8];
            }
#pragma unroll
            for (int m = 0; m < 4; m++)
#pragma unroll
                for (int n = 0; n < 4; n++)
                    acc[m][n] = __builtin_amdgcn_mfma_f32_16x16x32_bf16(
                        a[m], b[n], acc[m][n], 0, 0, 0);
        }
        __syncthreads();
    }

#pragma unroll
    for (int m = 0; m < 4; m++) {
#pragma unroll
        for (int r = 0; r < 4; r++) {
            int row = tileM + m0 + m * 16 + lq * 4 + r;
            if (row >= M) continue;
            bool q0 = cnt0 && (cnt0[row] > 0);
            bool q1 = cnt1 && (cnt1[row] > 0);
#pragma unroll
            for (int n = 0; n < 4; n++) {
                int col = tileN + n0 + n * 16 + lr;
                float v = acc[m][n][r];
                if (q0) v += bias0[col];
                if (q1) v += bias1[col];
                out[(size_t)row * D_DIM + col] = v;
            }
        }
    }
}

extern "C" void kernel_launch(void* const* d_in, const int* in_sizes, int n_in,
                              void* d_out, int out_size, void* d_ws, size_t ws_size,
                              hipStream_t stream) {
    const float* featA = (const float*)d_in[0];
    const float* featB = (const float*)d_in[1];
    const float* Waa = (const float*)d_in[2];
    const float* baa = (const float*)d_in[3];
    const float* Wab = (const float*)d_in[4];
    const float* bab = (const float*)d_in[5];
    const float* Wba = (const float*)d_in[6];
    const float* bba = (const float*)d_in[7];
    const int* src_aa = (const int*)d_in[8];
    const int* dst_aa = (const int*)d_in[9];
    const int* src_ab = (const int*)d_in[10];
    const int* dst_ab = (const int*)d_in[11];
    const int* src_ba = (const int*)d_in[12];
    const int* dst_ba = (const int*)d_in[13];

    int NA = in_sizes[0] / D_DIM, NB = in_sizes[1] / D_DIM;
    int Eaa = in_sizes[8], Eab = in_sizes[10], Eba = in_sizes[12];

    float* out = (float*)d_out;
    char* ws = (char*)d_ws;
    size_t off = 0;
    u16* Acat = (u16*)(ws + off); off += (size_t)NA * 1024 * 2;   // [NA][1024]: aa | ba
    u16* Aab  = (u16*)(ws + off); off += (size_t)NB * 512 * 2;    // [NB][512]
    u16* WtC  = (u16*)(ws + off); off += (size_t)512 * 1024 * 2;
    u16* WtAb = (u16*)(ws + off); off += (size_t)512 * 512 * 2;
    int* cnt_aa = (int*)(ws + off); off += (size_t)NA * 4;
    int* cnt_ba = (int*)(ws + off); off += (size_t)NA * 4;
    int* cnt_ab = (int*)(ws + off); off += (size_t)NB * 4;
    int* cur_aa = (int*)(ws + off); off += (size_t)NA * 4;
    int* cur_ba = (int*)(ws + off); off += (size_t)NA * 4;
    int* cur_ab = (int*)(ws + off); off += (size_t)NB * 4;
    int* csr_aa = (int*)(ws + off); off += (size_t)Eaa * 4;
    int* csr_ba = (int*)(ws + off); off += (size_t)Eba * 4;
    int* csr_ab = (int*)(ws + off); off += (size_t)Eab * 4;

    // zero counts only (aggregates are fully overwritten by pull)
    hipMemsetAsync(cnt_aa, 0, (size_t)(2 * NA + NB) * 4, stream);

    count_k<<<(Eaa + 255) / 256, 256, 0, stream>>>(dst_aa, cnt_aa, Eaa);
    count_k<<<(Eba + 255) / 256, 256, 0, stream>>>(dst_ba, cnt_ba, Eba);
    count_k<<<(Eab + 255) / 256, 256, 0, stream>>>(dst_ab, cnt_ab, Eab);

    scan_k<<<3, 1024, 0, stream>>>(cnt_aa, cur_aa, NA,
                                   cnt_ba, cur_ba, NA,
                                   cnt_ab, cur_ab, NB);

    fill_k<<<(Eaa + 255) / 256, 256, 0, stream>>>(src_aa, dst_aa, cur_aa, csr_aa, Eaa);
    fill_k<<<(Eba + 255) / 256, 256, 0, stream>>>(src_ba, dst_ba, cur_ba, csr_ba, Eba);
    fill_k<<<(Eab + 255) / 256, 256, 0, stream>>>(src_ab, dst_ab, cur_ab, csr_ab, Eab);

    prep_wt<<<(512 * 1024 + 512 * 512) / 256, 256, 0, stream>>>(Waa, Wba, Wab, WtC, WtAb);

    pull_k<<<(NA + 3) / 4, 256, 0, stream>>>(featA, cur_aa, cnt_aa, csr_aa,
                                             Acat, 1024, 0, NA);
    pull_k<<<(NA + 3) / 4, 256, 0, stream>>>(featB, cur_ba, cnt_ba, csr_ba,
                                             Acat, 1024, 512, NA);
    pull_k<<<(NB + 3) / 4, 256, 0, stream>>>(featA, cur_ab, cnt_ab, csr_ab,
                                             Aab, 512, 0, NB);

    dim3 blk(256);
    dim3 g1((NA + 127) / 128, 512 / 128);
    gemm_bias<1024><<<g1, blk, 0, stream>>>(Acat, WtC, out, baa, cnt_aa, bba, cnt_ba, NA);
    dim3 g2((NB + 127) / 128, 512 / 128);
    gemm_bias<512><<<g2, blk, 0, stream>>>(Aab, WtAb, out + (size_t)NA * D_DIM,
                                           bab, cnt_ab, nullptr, nullptr, NB);
}

// Round 4
// 544.392 us; speedup vs baseline: 3.5789x; 1.1000x over previous
//
#include <hip/hip_runtime.h>

typedef unsigned short u16;
typedef unsigned int u32;
typedef float f32x4 __attribute__((ext_vector_type(4)));
typedef short bfx8 __attribute__((ext_vector_type(8)));

#define D_DIM 512

__device__ __forceinline__ float bits2f(u32 b) {
    return __uint_as_float(b << 16);
}
__device__ __forceinline__ u16 f2b_bits(float f) {
    u32 u = __float_as_uint(f);
    u32 r = (u + 0x7fffu + ((u >> 16) & 1u)) >> 16;  // RNE
    return (u16)r;
}

// ---------------- degree count (3 etypes fused) ----------------
__global__ void count3_k(const int* __restrict__ d0, int* __restrict__ c0, int E0,
                         const int* __restrict__ d1, int* __restrict__ c1, int E1,
                         const int* __restrict__ d2, int* __restrict__ c2, int E2) {
    int i = blockIdx.x * 256 + threadIdx.x;
    if (i < E0) atomicAdd(&c0[d0[i]], 1);
    else if (i < E0 + E1) atomicAdd(&c1[d1[i - E0]], 1);
    else if (i < E0 + E1 + E2) atomicAdd(&c2[d2[i - E0 - E1]], 1);
}

// ---------------- exclusive prefix-sum (shuffle scan) ----------------
// 3 blocks, one per etype. Per 1024-chunk: wave shfl-scan + wave-carry.
__global__ __launch_bounds__(1024) void scan_k(
    const int* __restrict__ c0, int* __restrict__ o0, int n0,
    const int* __restrict__ c1, int* __restrict__ o1, int n1,
    const int* __restrict__ c2, int* __restrict__ o2, int n2) {
    const int* cnt = (blockIdx.x == 0) ? c0 : (blockIdx.x == 1) ? c1 : c2;
    int* cur = (blockIdx.x == 0) ? o0 : (blockIdx.x == 1) ? o1 : o2;
    int N = (blockIdx.x == 0) ? n0 : (blockIdx.x == 1) ? n1 : n2;
    __shared__ int wsum[16];
    int tid = threadIdx.x, lane = tid & 63, wv = tid >> 6;
    int carry = 0;
    for (int base = 0; base < N; base += 1024) {
        int v = (base + tid < N) ? cnt[base + tid] : 0;
        int x = v;
#pragma unroll
        for (int d = 1; d < 64; d <<= 1) {
            int t = __shfl_up(x, d, 64);
            if (lane >= d) x += t;
        }
        if (lane == 63) wsum[wv] = x;
        __syncthreads();
        if (wv == 0 && lane < 16) {
            int s = wsum[lane];
#pragma unroll
            for (int d = 1; d < 16; d <<= 1) {
                int t = __shfl_up(s, d, 64);
                if (lane >= d) s += t;
            }
            wsum[lane] = s;
        }
        __syncthreads();
        int woff = wv ? wsum[wv - 1] : 0;
        if (base + tid < N) cur[base + tid] = carry + woff + x - v;  // exclusive
        carry += wsum[15];
        __syncthreads();  // wsum stable until next chunk's writes
    }
}

// ---------------- CSR bucket fill (3 etypes fused) ----------------
// after this, cur[d] = inclusive prefix (end of bucket d)
__global__ void fill3_k(const int* __restrict__ s0, const int* __restrict__ d0,
                        int* __restrict__ u0, int* __restrict__ r0, int E0,
                        const int* __restrict__ s1, const int* __restrict__ d1,
                        int* __restrict__ u1, int* __restrict__ r1, int E1,
                        const int* __restrict__ s2, const int* __restrict__ d2,
                        int* __restrict__ u2, int* __restrict__ r2, int E2) {
    int i = blockIdx.x * 256 + threadIdx.x;
    if (i < E0) { int slot = atomicAdd(&u0[d0[i]], 1); r0[slot] = s0[i]; }
    else if (i < E0 + E1) { int j = i - E0; int slot = atomicAdd(&u1[d1[j]], 1); r1[slot] = s1[j]; }
    else if (i < E0 + E1 + E2) { int j = i - E0 - E1; int slot = atomicAdd(&u2[d2[j]], 1); r2[slot] = s2[j]; }
}

// ---------------- pull-mean (wave per dst node) ----------------
__global__ __launch_bounds__(256) void pull_k(
    const float* __restrict__ feat, const int* __restrict__ cur,
    const int* __restrict__ cnt, const int* __restrict__ csr,
    u16* __restrict__ agg, int ld, int colOff, int N) {
    int wid = threadIdx.x >> 6, lane = threadIdx.x & 63;
    int node = blockIdx.x * 4 + wid;
    if (node >= N) return;
    int end = cur[node];
    int c = cnt[node];
    int beg = end - c;
    float acc[8] = {};
    for (int j = beg; j < end; j++) {
        int s = csr[j];
        const float* fp = feat + (size_t)s * D_DIM + lane * 8;
        f32x4 v0 = *(const f32x4*)fp;
        f32x4 v1 = *(const f32x4*)(fp + 4);
        acc[0] += v0[0]; acc[1] += v0[1]; acc[2] += v0[2]; acc[3] += v0[3];
        acc[4] += v1[0]; acc[5] += v1[1]; acc[6] += v1[2]; acc[7] += v1[3];
    }
    float rc = 1.0f / (float)(c > 1 ? c : 1);
    u16* ap = agg + (size_t)node * ld + colOff + lane * 8;
    u16 o[8];
#pragma unroll
    for (int i = 0; i < 8; i++) o[i] = f2b_bits(acc[i] * rc);
    *(bfx8*)ap = *(bfx8*)o;
}

// ---------------- weight transpose f32 -> bf16 ----------------
__global__ void prep_wt(const float* __restrict__ Waa, const float* __restrict__ Wba,
                        const float* __restrict__ Wab,
                        u16* __restrict__ WtC, u16* __restrict__ WtAb) {
    int idx = blockIdx.x * 256 + threadIdx.x;
    if (idx < 512 * 1024) {
        int n = idx >> 10, k = idx & 1023;
        float v = (k < 512) ? Waa[k * 512 + n] : Wba[(k - 512) * 512 + n];
        WtC[idx] = f2b_bits(v);
    } else {
        int idx2 = idx - 512 * 1024;
        int n = idx2 >> 9, k = idx2 & 511;
        WtAb[idx2] = f2b_bits(Wab[k * 512 + n]);
    }
}

// ---------------- bf16 MFMA GEMM, f32 out ----------------
// out[m][n] = sum_k A[m][k] * Bt[n][k]  (+ cnt-masked f32 biases)
// 128x128 tile, BK=64, 4 waves, 16x16x32 MFMA, XOR-swizzled LDS.
// v2: prefetch double-buffer (T3-min) + bijective XCD-chunk swizzle with
// N-major tile order so the 4 N-tiles of one M-panel share an XCD's L2.
template <int KT>
__global__ __launch_bounds__(256) void gemm_bias(
    const u16* __restrict__ A, const u16* __restrict__ Bt,
    float* __restrict__ out,
    const float* __restrict__ bias0, const int* __restrict__ cnt0,
    const float* __restrict__ bias1, const int* __restrict__ cnt1,
    int M) {
    constexpr int BK = 64;
    constexpr int NT = KT / BK;
    __shared__ __align__(16) u16 As[2][128 * BK];
    __shared__ __align__(16) u16 Bs[2][128 * BK];

    int tid = threadIdx.x;
    int wid = tid >> 6, lane = tid & 63;

    // bijective XCD swizzle (m204), N-major tile order
    int nwg = gridDim.x;
    int orig = blockIdx.x;
    int q = nwg >> 3, r = nwg & 7, xc = orig & 7;
    int idx = (xc < r ? xc * (q + 1) : r * (q + 1) + (xc - r) * q) + (orig >> 3);
    int tileN = (idx & 3) * 128;
    int tileM = (idx >> 2) * 128;

    int wm = wid >> 1, wn = wid & 1;
    int m0 = wm * 64, n0 = wn * 64;

    int l8 = lane >> 3;
    int cc = (lane & 7) ^ l8;  // pre-swizzled source chunk

    f32x4 acc[4][4] = {};
    int lq = lane >> 4, lr = lane & 15;

    auto stage = [&](int buf, int k0) {
#pragma unroll
        for (int i = 0; i < 4; i++) {
            int jj = wid * 4 + i;
            int row = tileM + jj * 8 + l8;
            if (row > M - 1) row = M - 1;
            const u16* srcA = A + (size_t)row * KT + k0 + cc * 8;
            __builtin_amdgcn_global_load_lds(
                (const __attribute__((address_space(1))) void*)srcA,
                (__attribute__((address_space(3))) void*)&As[buf][jj * 8 * BK],
                16, 0, 0);
            int nrow = tileN + jj * 8 + l8;
            const u16* srcB = Bt + (size_t)nrow * KT + k0 + cc * 8;
            __builtin_amdgcn_global_load_lds(
                (const __attribute__((address_space(1))) void*)srcB,
                (__attribute__((address_space(3))) void*)&Bs[buf][jj * 8 * BK],
                16, 0, 0);
        }
    };

    stage(0, 0);
    __syncthreads();
    int cur = 0;

    for (int t = 0; t < NT; ++t) {
        if (t + 1 < NT) stage(cur ^ 1, (t + 1) * BK);  // prefetch next tile
#pragma unroll
        for (int kk = 0; kk < 2; kk++) {
            bfx8 a[4], b[4];
#pragma unroll
            for (int m = 0; m < 4; m++) {
                int rr = m0 + m * 16 + lr;
                int cp = ((kk << 2) | lq) ^ (rr & 7);
                a[m] = *(const bfx8*)&As[cur][rr * BK + cp * 8];
            }
#pragma unroll
            for (int n = 0; n < 4; n++) {
                int rr = n0 + n * 16 + lr;
                int cp = ((kk << 2) | lq) ^ (rr & 7);
                b[n] = *(const bfx8*)&Bs[cur][rr * BK + cp * 8];
            }
#pragma unroll
            for (int m = 0; m < 4; m++)
#pragma unroll
                for (int n = 0; n < 4; n++)
                    acc[m][n] = __builtin_amdgcn_mfma_f32_16x16x32_bf16(
                        a[m], b[n], acc[m][n], 0, 0, 0);
        }
        __syncthreads();  // drains vmcnt(0): prefetch done, buffer swap safe
        cur ^= 1;
    }

#pragma unroll
    for (int m = 0; m < 4; m++) {
#pragma unroll
        for (int r2 = 0; r2 < 4; r2++) {
            int row = tileM + m0 + m * 16 + lq * 4 + r2;
            if (row >= M) continue;
            bool q0 = cnt0 && (cnt0[row] > 0);
            bool q1 = cnt1 && (cnt1[row] > 0);
#pragma unroll
            for (int n = 0; n < 4; n++) {
                int col = tileN + n0 + n * 16 + lr;
                float v = acc[m][n][r2];
                if (q0) v += bias0[col];
                if (q1) v += bias1[col];
                out[(size_t)row * D_DIM + col] = v;
            }
        }
    }
}

extern "C" void kernel_launch(void* const* d_in, const int* in_sizes, int n_in,
                              void* d_out, int out_size, void* d_ws, size_t ws_size,
                              hipStream_t stream) {
    const float* featA = (const float*)d_in[0];
    const float* featB = (const float*)d_in[1];
    const float* Waa = (const float*)d_in[2];
    const float* baa = (const float*)d_in[3];
    const float* Wab = (const float*)d_in[4];
    const float* bab = (const float*)d_in[5];
    const float* Wba = (const float*)d_in[6];
    const float* bba = (const float*)d_in[7];
    const int* src_aa = (const int*)d_in[8];
    const int* dst_aa = (const int*)d_in[9];
    const int* src_ab = (const int*)d_in[10];
    const int* dst_ab = (const int*)d_in[11];
    const int* src_ba = (const int*)d_in[12];
    const int* dst_ba = (const int*)d_in[13];

    int NA = in_sizes[0] / D_DIM, NB = in_sizes[1] / D_DIM;
    int Eaa = in_sizes[8], Eab = in_sizes[10], Eba = in_sizes[12];

    float* out = (float*)d_out;
    char* ws = (char*)d_ws;
    size_t off = 0;
    u16* Acat = (u16*)(ws + off); off += (size_t)NA * 1024 * 2;   // [NA][1024]: aa | ba
    u16* Aab  = (u16*)(ws + off); off += (size_t)NB * 512 * 2;    // [NB][512]
    u16* WtC  = (u16*)(ws + off); off += (size_t)512 * 1024 * 2;
    u16* WtAb = (u16*)(ws + off); off += (size_t)512 * 512 * 2;
    int* cnt_aa = (int*)(ws + off); off += (size_t)NA * 4;
    int* cnt_ba = (int*)(ws + off); off += (size_t)NA * 4;
    int* cnt_ab = (int*)(ws + off); off += (size_t)NB * 4;
    int* cur_aa = (int*)(ws + off); off += (size_t)NA * 4;
    int* cur_ba = (int*)(ws + off); off += (size_t)NA * 4;
    int* cur_ab = (int*)(ws + off); off += (size_t)NB * 4;
    int* csr_aa = (int*)(ws + off); off += (size_t)Eaa * 4;
    int* csr_ba = (int*)(ws + off); off += (size_t)Eba * 4;
    int* csr_ab = (int*)(ws + off); off += (size_t)Eab * 4;

    // zero counts only (aggregates fully overwritten by pull)
    hipMemsetAsync(cnt_aa, 0, (size_t)(2 * NA + NB) * 4, stream);

    int Etot = Eaa + Eba + Eab;
    count3_k<<<(Etot + 255) / 256, 256, 0, stream>>>(
        dst_aa, cnt_aa, Eaa, dst_ba, cnt_ba, Eba, dst_ab, cnt_ab, Eab);

    scan_k<<<3, 1024, 0, stream>>>(cnt_aa, cur_aa, NA,
                                   cnt_ba, cur_ba, NA,
                                   cnt_ab, cur_ab, NB);

    fill3_k<<<(Etot + 255) / 256, 256, 0, stream>>>(
        src_aa, dst_aa, cur_aa, csr_aa, Eaa,
        src_ba, dst_ba, cur_ba, csr_ba, Eba,
        src_ab, dst_ab, cur_ab, csr_ab, Eab);

    prep_wt<<<(512 * 1024 + 512 * 512) / 256, 256, 0, stream>>>(Waa, Wba, Wab, WtC, WtAb);

    pull_k<<<(NA + 3) / 4, 256, 0, stream>>>(featA, cur_aa, cnt_aa, csr_aa,
                                             Acat, 1024, 0, NA);
    pull_k<<<(NA + 3) / 4, 256, 0, stream>>>(featB, cur_ba, cnt_ba, csr_ba,
                                             Acat, 1024, 512, NA);
    pull_k<<<(NB + 3) / 4, 256, 0, stream>>>(featA, cur_ab, cnt_ab, csr_ab,
                                             Aab, 512, 0, NB);

    dim3 blk(256);
    int nwg1 = ((NA + 127) / 128) * 4;
    gemm_bias<1024><<<nwg1, blk, 0, stream>>>(Acat, WtC, out, baa, cnt_aa, bba, cnt_ba, NA);
    int nwg2 = ((NB + 127) / 128) * 4;
    gemm_bias<512><<<nwg2, blk, 0, stream>>>(Aab, WtAb, out + (size_t)NA * D_DIM,
                                             bab, cnt_ab, nullptr, nullptr, NB);
}